// Round 10
// baseline (1330.379 us; speedup 1.0000x reference)
//
#include <hip/hip_runtime.h>
#include <hip/hip_bf16.h>

#define B_ 64
#define N_ 1024
#define E_ 512
#define D_ 1024
#define M_ 16
#define T_ 12
#define P_ 2048
#define HS_ 2048
#define HN_ 64
#define C_ 4
#define NH_ 8
#define DH_ 64

typedef __attribute__((ext_vector_type(8))) short bf16x8;
typedef __attribute__((ext_vector_type(4))) float f32x4;

__device__ __forceinline__ float bf2f(unsigned int u) {
    union { unsigned int i; float f; } c; c.i = (u & 0xffffu) << 16; return c.f;
}
__device__ __forceinline__ unsigned short f2bf(float f) {
    union { float f; unsigned int i; } c; c.f = f;
    unsigned int x = c.i;
    unsigned int r = x + 0x7fffu + ((x >> 16) & 1u);
    return (unsigned short)(r >> 16);
}

// ---------------- init state + decay/invs tables ----------------
__global__ void init_kernel(unsigned short* s_a_bf, float* a_a, float* a_o, float* z,
                            const float* __restrict__ raw_a, const float* __restrict__ raw_o,
                            float* __restrict__ da, float* __restrict__ dz,
                            float* __restrict__ invsa, float* __restrict__ invso) {
    int i = blockIdx.x * 256 + threadIdx.x;
    if (i < B_ * P_) { a_a[i] = 0.f; a_o[i] = 0.f; s_a_bf[i] = 0; }
    if (i < B_ * D_) z[i] = 0.f;
    if (i < P_) {
        float a = 1.f / (1.f + expf(raw_a[i]));
        float o = 1.f / (1.f + expf(raw_o[i]));
        da[i] = a; dz[i] = o;
        float ba = 1.f, bo = 1.f;
        for (int t = 0; t < T_; t++) {
            ba = a * ba + 1.f;
            bo = o * bo + 1.f;
            invsa[t * P_ + i] = 1.0f / sqrtf(ba + 1e-8f);
            invso[t * P_ + i] = 1.0f / sqrtf(bo + 1e-8f);
        }
    }
}

// ---------------- f32 -> bf16 conversion ----------------
__global__ __launch_bounds__(256) void cvt_bf16_kernel(const float* __restrict__ in,
                                                       unsigned short* __restrict__ out, int n4) {
    int i = blockIdx.x * 256 + threadIdx.x;
    if (i < n4) {
        float4 v = ((const float4*)in)[i];
        ushort4 o;
        o.x = f2bf(v.x); o.y = f2bf(v.y); o.z = f2bf(v.z); o.w = f2bf(v.w);
        ((ushort4*)out)[i] = o;
    }
}

// ---------------- consolidated multi-segment cvt ----------------
__global__ __launch_bounds__(256) void cvt_all_kernel(
    const float* s0, unsigned short* d0, int n0,
    const float* s1, unsigned short* d1, int n1,
    const float* s2, unsigned short* d2, int n2,
    const float* s3, unsigned short* d3, int n3,
    const float* s4, unsigned short* d4, int n4,
    const float* s5, unsigned short* d5, int n5) {
    int total = n0 + n1 + n2 + n3 + n4 + n5;
    for (int i = blockIdx.x * 256 + threadIdx.x; i < total; i += gridDim.x * 256) {
        const float* s; unsigned short* d; int j = i;
        if (j < n0) { s = s0; d = d0; }
        else { j -= n0;
        if (j < n1) { s = s1; d = d1; }
        else { j -= n1;
        if (j < n2) { s = s2; d = d2; }
        else { j -= n2;
        if (j < n3) { s = s3; d = d3; }
        else { j -= n3;
        if (j < n4) { s = s4; d = d4; }
        else { j -= n4; s = s5; d = d5; } } } } }
        float4 v = ((const float4*)s)[j];
        ushort4 o;
        o.x = f2bf(v.x); o.y = f2bf(v.y); o.z = f2bf(v.z); o.w = f2bf(v.w);
        ((ushort4*)d)[j] = o;
    }
}

// ---------------- interleave gate/cand rows ----------------
__global__ __launch_bounds__(256) void cvt_ilv_kernel(const float* __restrict__ g,
                                                      const float* __restrict__ c,
                                                      unsigned short* __restrict__ out) {
    int r = blockIdx.x;  // 0..2047
    const float* src = (r & 1) ? (c + (size_t)(r >> 1) * 1536) : (g + (size_t)(r >> 1) * 1536);
    for (int k = threadIdx.x * 4; k < 1536; k += 1024) {
        float4 v = *(const float4*)(src + k);
        ushort4 o;
        o.x = f2bf(v.x); o.y = f2bf(v.y); o.z = f2bf(v.z); o.w = f2bf(v.w);
        *(ushort4*)(out + (size_t)r * 1536 + k) = o;
    }
}

// ---------------- transpose + cvt: out[c][r] = bf16(in[r][c]) ----------------
__global__ __launch_bounds__(256) void transpose_cvt_kernel(const float* __restrict__ in,
                                                            unsigned short* __restrict__ out,
                                                            int R, int Ccols) {
    __shared__ float tb[32][33];
    int c0 = blockIdx.x * 32, r0 = blockIdx.y * 32;
    int tx = threadIdx.x & 31, ty = threadIdx.x >> 5;
#pragma unroll
    for (int i = 0; i < 32; i += 8) tb[ty + i][tx] = in[(size_t)(r0 + ty + i) * Ccols + c0 + tx];
    __syncthreads();
#pragma unroll
    for (int i = 0; i < 32; i += 8) out[(size_t)(c0 + ty + i) * R + r0 + tx] = f2bf(tb[tx][ty + i]);
}

// ---------------- combined query bias: bc = Wq@q_b + bq ----------------
__global__ __launch_bounds__(256) void bcomb_kernel(const float* __restrict__ in_proj_w,
                                                    const float* __restrict__ in_proj_b,
                                                    const float* __restrict__ q_b,
                                                    float* __restrict__ bc) {
    int e = blockIdx.x * 256 + threadIdx.x;
    if (e < E_) {
        const float* wr = in_proj_w + (size_t)e * E_;
        float s = in_proj_b[e];
        for (int k = 0; k < E_; k += 4) {
            float4 w4 = *(const float4*)(wr + k);
            float4 q4 = *(const float4*)(q_b + k);
            s += w4.x * q4.x + w4.y * q4.y + w4.z * q4.z + w4.w * q4.w;
        }
        bc[e] = s;
    }
}

// ---------------- br[h*512+j] = sum_e Wk[h*64+e][j] * bc[h*64+e] ----------------
__global__ __launch_bounds__(256) void br_kernel(const float* __restrict__ in_proj_w,
                                                 const float* __restrict__ bc,
                                                 float* __restrict__ br) {
    int g = blockIdx.x * 256 + threadIdx.x;  // 0..4095
    int h = g >> 9, j = g & 511;
    const float* Wk = in_proj_w + (size_t)E_ * E_;
    float s = 0.f;
    for (int e = 0; e < 64; e++) {
        s += Wk[(size_t)(h * 64 + e) * E_ + j] * bc[h * 64 + e];
    }
    br[g] = s;
}

// ---------------- r for t=0 (s_a == 0): r_bf[b][j] = bf16(0.125 * br[j]) ----------------
__global__ __launch_bounds__(256) void r0_kernel(const float* __restrict__ brv,
                                                 unsigned short* __restrict__ r_bf) {
    int i = blockIdx.x * 256 + threadIdx.x;  // 0 .. 64*4096-1
    if (i < B_ * 4096) {
        r_bf[i] = f2bf(0.125f * brv[i & 4095]);
    }
}

// ---------------- big bf16 MFMA GEMM (128x128 tile) + XCD swizzle ----------------
template <bool HAS_BIAS>
__global__ __launch_bounds__(256) void gemm_bt_kernel(const unsigned short* __restrict__ A,
                                                      const unsigned short* __restrict__ Bt,
                                                      const float* __restrict__ bias,
                                                      unsigned short* __restrict__ C,
                                                      int M, int N, int K) {
    __shared__ __align__(16) unsigned short ldsA[2][4096];
    __shared__ __align__(16) unsigned short ldsB[2][4096];
    int id = blockIdx.y * gridDim.x + blockIdx.x;
    int nwg = gridDim.x * gridDim.y;
    int swz = (id & 7) * (nwg >> 3) + (id >> 3);
    int bx = swz % gridDim.x, by = swz / gridDim.x;
    int m0 = by * 128;
    int n0 = bx * 128;
    int tid = threadIdx.x;
    int wv = tid >> 6, l = tid & 63;
    int wr = wv >> 1, wc = wv & 1;
    int lr = l & 15, lg = l >> 4;
    f32x4 acc[4][4] = {};

    auto stage = [&](int buf, int kt) {
        int k0 = kt * 32;
#pragma unroll
        for (int i = 0; i < 2; i++) {
            int tsk = tid + 256 * i;
            int r = tsk >> 2, g = tsk & 3;
            int gs = (g ^ (r & 3)) * 8;
            __builtin_amdgcn_global_load_lds(
                (const __attribute__((address_space(1))) void*)(A + (size_t)(m0 + r) * K + k0 + gs),
                (__attribute__((address_space(3))) void*)&ldsA[buf][tsk * 8], 16, 0, 0);
        }
#pragma unroll
        for (int i = 0; i < 2; i++) {
            int tsk = tid + 256 * i;
            int r = tsk >> 2, g = tsk & 3;
            int gs = (g ^ (r & 3)) * 8;
            __builtin_amdgcn_global_load_lds(
                (const __attribute__((address_space(1))) void*)(Bt + (size_t)(n0 + r) * K + k0 + gs),
                (__attribute__((address_space(3))) void*)&ldsB[buf][tsk * 8], 16, 0, 0);
        }
    };

    int nt = K >> 5;
    stage(0, 0);
    for (int t = 0; t < nt; t++) {
        int cur = t & 1;
        if (t + 1 < nt) {
            stage(cur ^ 1, t + 1);
            asm volatile("s_waitcnt vmcnt(4)" ::: "memory");
        } else {
            asm volatile("s_waitcnt vmcnt(0)" ::: "memory");
        }
        __builtin_amdgcn_s_barrier();
        bf16x8 af[4], bfr[4];
#pragma unroll
        for (int mi = 0; mi < 4; mi++) {
            int r = wr * 64 + mi * 16 + lr;
            af[mi] = *(const bf16x8*)&ldsA[cur][r * 32 + ((lg ^ (r & 3)) << 3)];
        }
#pragma unroll
        for (int ni = 0; ni < 4; ni++) {
            int c = wc * 64 + ni * 16 + lr;
            bfr[ni] = *(const bf16x8*)&ldsB[cur][c * 32 + ((lg ^ (c & 3)) << 3)];
        }
#pragma unroll
        for (int mi = 0; mi < 4; mi++)
#pragma unroll
            for (int ni = 0; ni < 4; ni++)
                acc[mi][ni] = __builtin_amdgcn_mfma_f32_16x16x32_bf16(af[mi], bfr[ni], acc[mi][ni], 0, 0, 0);
        __builtin_amdgcn_s_barrier();
    }
#pragma unroll
    for (int ni = 0; ni < 4; ni++) {
        int col = n0 + wc * 64 + ni * 16 + lr;
        float bv = HAS_BIAS ? bias[col] : 0.0f;
#pragma unroll
        for (int mi = 0; mi < 4; mi++) {
            int row = m0 + wr * 64 + mi * 16 + lg * 4;
#pragma unroll
            for (int r = 0; r < 4; r++) {
                C[(size_t)(row + r) * N + col] = f2bf(acc[mi][ni][r] + bv);
            }
        }
    }
}

// ---------------- wide GEMM: 128x256 tile (halves A re-reads for small-N GEMMs like Vproj) ----------------
__global__ __launch_bounds__(256) void gemm_bt_wide_kernel(const unsigned short* __restrict__ A,
                                                           const unsigned short* __restrict__ Bt,
                                                           const float* __restrict__ bias,
                                                           unsigned short* __restrict__ C,
                                                           int M, int N, int K) {
    __shared__ __align__(16) unsigned short ldsA[2][4096];   // 128 x 32
    __shared__ __align__(16) unsigned short ldsB[2][8192];   // 256 x 32
    int id = blockIdx.y * gridDim.x + blockIdx.x;
    int nwg = gridDim.x * gridDim.y;
    int swz = (id & 7) * (nwg >> 3) + (id >> 3);
    int bx = swz % gridDim.x, by = swz / gridDim.x;
    int m0 = by * 128;
    int n0 = bx * 256;
    int tid = threadIdx.x;
    int wv = tid >> 6, l = tid & 63;
    int wr = wv >> 1, wc = wv & 1;
    int lr = l & 15, lg = l >> 4;
    f32x4 acc[4][8] = {};

    auto stage = [&](int buf, int kt) {
        int k0 = kt * 32;
#pragma unroll
        for (int i = 0; i < 2; i++) {
            int tsk = tid + 256 * i;
            int r = tsk >> 2, g = tsk & 3;
            int gs = (g ^ (r & 3)) * 8;
            __builtin_amdgcn_global_load_lds(
                (const __attribute__((address_space(1))) void*)(A + (size_t)(m0 + r) * K + k0 + gs),
                (__attribute__((address_space(3))) void*)&ldsA[buf][tsk * 8], 16, 0, 0);
        }
#pragma unroll
        for (int i = 0; i < 4; i++) {
            int tsk = tid + 256 * i;
            int r = tsk >> 2, g = tsk & 3;
            int gs = (g ^ (r & 3)) * 8;
            __builtin_amdgcn_global_load_lds(
                (const __attribute__((address_space(1))) void*)(Bt + (size_t)(n0 + r) * K + k0 + gs),
                (__attribute__((address_space(3))) void*)&ldsB[buf][tsk * 8], 16, 0, 0);
        }
    };

    int nt = K >> 5;
    stage(0, 0);
    for (int t = 0; t < nt; t++) {
        int cur = t & 1;
        if (t + 1 < nt) {
            stage(cur ^ 1, t + 1);
            asm volatile("s_waitcnt vmcnt(6)" ::: "memory");
        } else {
            asm volatile("s_waitcnt vmcnt(0)" ::: "memory");
        }
        __builtin_amdgcn_s_barrier();
        bf16x8 af[4], bfr[8];
#pragma unroll
        for (int mi = 0; mi < 4; mi++) {
            int r = wr * 64 + mi * 16 + lr;
            af[mi] = *(const bf16x8*)&ldsA[cur][r * 32 + ((lg ^ (r & 3)) << 3)];
        }
#pragma unroll
        for (int ni = 0; ni < 8; ni++) {
            int c = wc * 128 + ni * 16 + lr;
            bfr[ni] = *(const bf16x8*)&ldsB[cur][c * 32 + ((lg ^ (c & 3)) << 3)];
        }
#pragma unroll
        for (int mi = 0; mi < 4; mi++)
#pragma unroll
            for (int ni = 0; ni < 8; ni++)
                acc[mi][ni] = __builtin_amdgcn_mfma_f32_16x16x32_bf16(af[mi], bfr[ni], acc[mi][ni], 0, 0, 0);
        __builtin_amdgcn_s_barrier();
    }
#pragma unroll
    for (int ni = 0; ni < 8; ni++) {
        int col = n0 + wc * 128 + ni * 16 + lr;
        float bv = bias[col];
#pragma unroll
        for (int mi = 0; mi < 4; mi++) {
            int row = m0 + wr * 64 + mi * 16 + lg * 4;
#pragma unroll
            for (int r = 0; r < 4; r++) {
                C[(size_t)(row + r) * N + col] = f2bf(acc[mi][ni][r] + bv);
            }
        }
    }
}

// ---------------- batched (z=head) strided GEMM for G ----------------
__global__ __launch_bounds__(256) void gemm_hb_kernel(const unsigned short* __restrict__ A0, int lda, size_t sAz,
                                                      const unsigned short* __restrict__ B0, int ldb, size_t sBz,
                                                      unsigned short* __restrict__ C0, int ldc, size_t sCz,
                                                      int K) {
    __shared__ __align__(16) unsigned short ldsA[2][4096];
    __shared__ __align__(16) unsigned short ldsB[2][4096];
    const unsigned short* A = A0 + blockIdx.z * sAz;
    const unsigned short* Bt = B0 + blockIdx.z * sBz;
    unsigned short* C = C0 + blockIdx.z * sCz;
    int m0 = blockIdx.y * 128, n0 = blockIdx.x * 128;
    int tid = threadIdx.x;
    int wv = tid >> 6, l = tid & 63;
    int wr = wv >> 1, wc = wv & 1;
    int lr = l & 15, lg = l >> 4;
    f32x4 acc[4][4] = {};

    auto stage = [&](int buf, int kt) {
        int k0 = kt * 32;
#pragma unroll
        for (int i = 0; i < 2; i++) {
            int tsk = tid + 256 * i;
            int r = tsk >> 2, g = tsk & 3;
            int gs = (g ^ (r & 3)) * 8;
            __builtin_amdgcn_global_load_lds(
                (const __attribute__((address_space(1))) void*)(A + (size_t)(m0 + r) * lda + k0 + gs),
                (__attribute__((address_space(3))) void*)&ldsA[buf][tsk * 8], 16, 0, 0);
        }
#pragma unroll
        for (int i = 0; i < 2; i++) {
            int tsk = tid + 256 * i;
            int r = tsk >> 2, g = tsk & 3;
            int gs = (g ^ (r & 3)) * 8;
            __builtin_amdgcn_global_load_lds(
                (const __attribute__((address_space(1))) void*)(Bt + (size_t)(n0 + r) * ldb + k0 + gs),
                (__attribute__((address_space(3))) void*)&ldsB[buf][tsk * 8], 16, 0, 0);
        }
    };

    int nt = K >> 5;
    stage(0, 0);
    for (int t = 0; t < nt; t++) {
        int cur = t & 1;
        if (t + 1 < nt) {
            stage(cur ^ 1, t + 1);
            asm volatile("s_waitcnt vmcnt(4)" ::: "memory");
        } else {
            asm volatile("s_waitcnt vmcnt(0)" ::: "memory");
        }
        __builtin_amdgcn_s_barrier();
        bf16x8 af[4], bfr[4];
#pragma unroll
        for (int mi = 0; mi < 4; mi++) {
            int r = wr * 64 + mi * 16 + lr;
            af[mi] = *(const bf16x8*)&ldsA[cur][r * 32 + ((lg ^ (r & 3)) << 3)];
        }
#pragma unroll
        for (int ni = 0; ni < 4; ni++) {
            int c = wc * 64 + ni * 16 + lr;
            bfr[ni] = *(const bf16x8*)&ldsB[cur][c * 32 + ((lg ^ (c & 3)) << 3)];
        }
#pragma unroll
        for (int mi = 0; mi < 4; mi++)
#pragma unroll
            for (int ni = 0; ni < 4; ni++)
                acc[mi][ni] = __builtin_amdgcn_mfma_f32_16x16x32_bf16(af[mi], bfr[ni], acc[mi][ni], 0, 0, 0);
        __builtin_amdgcn_s_barrier();
    }
#pragma unroll
    for (int ni = 0; ni < 4; ni++) {
        int col = n0 + wc * 64 + ni * 16 + lr;
#pragma unroll
        for (int mi = 0; mi < 4; mi++) {
            int row = m0 + wr * 64 + mi * 16 + lg * 4;
#pragma unroll
            for (int r = 0; r < 4; r++) {
                C[(size_t)(row + r) * ldc + col] = f2bf(acc[mi][ni][r]);
            }
        }
    }
}

// ---------------- fused batch-64 GEMM: 64x16 tile, 4-wave K-split, in-block reduce + epilogue ----------------
template <int EPI>
__global__ __launch_bounds__(256) void gemmNK_kernel(const unsigned short* __restrict__ A,
                                                     const unsigned short* __restrict__ W,
                                                     const float* __restrict__ bias0,
                                                     const float* __restrict__ bias1,
                                                     const float* __restrict__ zn32,
                                                     void* __restrict__ outp,
                                                     int N, int K) {
    __shared__ __align__(16) unsigned short ldsA[4][2][2048];
    __shared__ __align__(16) unsigned short ldsB[4][2][512];
    int n0 = blockIdx.x * 16;
    int tid = threadIdx.x;
    int w = tid >> 6, l = tid & 63;
    int Kw = K >> 2;
    int kb = w * Kw;
    int lr = l & 15, lg = l >> 4;
    int ar = l >> 2, ag = l & 3;
    f32x4 acc[4] = {};

    auto stage = [&](int buf, int kt) {
        int k0 = kb + (kt << 5);
#pragma unroll
        for (int i = 0; i < 4; i++) {
            int row = i * 16 + ar;
            int gs = (ag ^ (row & 3)) << 3;
            __builtin_amdgcn_global_load_lds(
                (const __attribute__((address_space(1))) void*)(A + (size_t)row * K + k0 + gs),
                (__attribute__((address_space(3))) void*)&ldsA[w][buf][i * 512 + l * 8], 16, 0, 0);
        }
        {
            int col = ar;
            int gs = (ag ^ (col & 3)) << 3;
            __builtin_amdgcn_global_load_lds(
                (const __attribute__((address_space(1))) void*)(W + (size_t)(n0 + col) * K + k0 + gs),
                (__attribute__((address_space(3))) void*)&ldsB[w][buf][l * 8], 16, 0, 0);
        }
    };

    int nt = Kw >> 5;
    stage(0, 0);
    for (int t = 0; t < nt; t++) {
        int cur = t & 1;
        if (t + 1 < nt) {
            stage(cur ^ 1, t + 1);
            asm volatile("s_waitcnt vmcnt(5)" ::: "memory");
        } else {
            asm volatile("s_waitcnt vmcnt(0)" ::: "memory");
        }
        bf16x8 bf = *(const bf16x8*)&ldsB[w][cur][lr * 32 + ((lg ^ (lr & 3)) << 3)];
#pragma unroll
        for (int mi = 0; mi < 4; mi++) {
            int rr = mi * 16 + lr;
            bf16x8 af = *(const bf16x8*)&ldsA[w][cur][rr * 32 + ((lg ^ (rr & 3)) << 3)];
            acc[mi] = __builtin_amdgcn_mfma_f32_16x16x32_bf16(af, bf, acc[mi], 0, 0, 0);
        }
    }
    __syncthreads();
    float* red = (float*)&ldsA[0][0][0];  // [4][64][16]
#pragma unroll
    for (int mi = 0; mi < 4; mi++) {
        int row = mi * 16 + lg * 4;
#pragma unroll
        for (int q = 0; q < 4; q++) red[w * 1024 + (row + q) * 16 + lr] = acc[mi][q];
    }
    __syncthreads();
    int b = tid >> 2, c4 = (tid & 3) << 2;
    f32x4 s = *(f32x4*)&red[b * 16 + c4];
#pragma unroll
    for (int ww = 1; ww < 4; ww++) {
        f32x4 v = *(f32x4*)&red[ww * 1024 + b * 16 + c4];
        s[0] += v[0]; s[1] += v[1]; s[2] += v[2]; s[3] += v[3];
    }
    int col = n0 + c4;
    if (EPI == 0) {
        unsigned short* out = (unsigned short*)outp;
        ushort4 o;
        o.x = f2bf(0.125f * (s[0] + bias0[col + 0]));
        o.y = f2bf(0.125f * (s[1] + bias0[col + 1]));
        o.z = f2bf(0.125f * (s[2] + bias0[col + 2]));
        o.w = f2bf(0.125f * (s[3] + bias0[col + 3]));
        *(ushort4*)(out + (size_t)b * N + col) = o;
    } else if (EPI == 1) {
        float* out = (float*)outp;
        *(f32x4*)(out + (size_t)b * N + col) = s;
    } else if (EPI == 2) {
        unsigned short* out = (unsigned short*)outp;
        int j0 = col >> 1;
#pragma unroll
        for (int pp = 0; pp < 2; pp++) {
            int j = j0 + pp;
            float g = 1.0f / (1.0f + expf(-(s[pp * 2] + bias0[j])));
            float h = tanhf(s[pp * 2 + 1] + bias1[j]);
            float zb = (1.0f - g) * zn32[(size_t)b * D_ + j] + g * h;
            out[(size_t)b * 1536 + j] = f2bf(zb);
        }
    } else if (EPI == 3) {
        unsigned short* out = (unsigned short*)outp;
        ushort4 o;
#pragma unroll
        for (int j = 0; j < 4; j++) {
            float pre = s[j] + bias0[col + j];
            float val = 0.5f * pre * (1.0f + erff(pre * 0.70710678118654752f));
            ((unsigned short*)&o)[j] = f2bf(val);
        }
        *(ushort4*)(out + (size_t)b * N + col) = o;
    } else {  // EPI == 4: transposed f32 out[col][b]
        float* out = (float*)outp;
#pragma unroll
        for (int j = 0; j < 4; j++) {
            out[(size_t)(col + j) * 64 + b] = s[j] + bias0[col + j];
        }
    }
}

// ---------------- scores: S[b][h][n] = X[b,n,:] . r[b][h*512+:] (MFMA) ----------------
__global__ __launch_bounds__(256) void scoreX_kernel(const unsigned short* __restrict__ X,
                                                     const unsigned short* __restrict__ r_bf,
                                                     float* __restrict__ S) {
    int b = blockIdx.y;
    int n0 = blockIdx.x * 128;
    int tid = threadIdx.x;
    int wv = tid >> 6, l = tid & 63;
    int lr = l & 15, lg = l >> 4;
    const unsigned short* Xb = X + ((size_t)b * 1024 + n0) * 512;
    const unsigned short* rb = r_bf + (size_t)b * 4096 + (size_t)(lr & 7) * 512 + lg * 8;
    f32x4 acc[2] = {};
#pragma unroll
    for (int kt = 0; kt < 16; kt++) {
        int k0 = kt * 32;
        bf16x8 bfrag = *(const bf16x8*)(rb + k0);
#pragma unroll
        for (int mi = 0; mi < 2; mi++) {
            int row = (wv * 2 + mi) * 16 + lr;
            bf16x8 afrag = *(const bf16x8*)(Xb + (size_t)row * 512 + k0 + lg * 8);
            acc[mi] = __builtin_amdgcn_mfma_f32_16x16x32_bf16(afrag, bfrag, acc[mi], 0, 0, 0);
        }
    }
    if (lr < 8) {
#pragma unroll
        for (int mi = 0; mi < 2; mi++) {
            int rowbase = (wv * 2 + mi) * 16 + lg * 4;
#pragma unroll
            for (int q = 0; q < 4; q++) {
                S[((size_t)b * 8 + lr) * 1024 + n0 + rowbase + q] = acc[mi][q];
            }
        }
    }
}

// ---------------- softmax(S) + V-pass per (b,h), uint4 V loads ----------------
__global__ __launch_bounds__(256) void attnV_kernel(const float* __restrict__ S,
                                                    const unsigned short* __restrict__ vbuf,
                                                    unsigned short* __restrict__ o_bf) {
    int bh = blockIdx.x;
    int b = bh >> 3, h = bh & 7;
    __shared__ float sc[N_];
    __shared__ float red[8];
    __shared__ float opart[4][DH_];
    int tid = threadIdx.x;
    int w = tid >> 6, lane = tid & 63;
    const float* Ss = S + ((size_t)b * 8 + h) * 1024;
    float myv[4];
#pragma unroll
    for (int i = 0; i < 4; i++) myv[i] = Ss[tid + i * 256];
    float m = fmaxf(fmaxf(myv[0], myv[1]), fmaxf(myv[2], myv[3]));
#pragma unroll
    for (int off = 32; off >= 1; off >>= 1) m = fmaxf(m, __shfl_xor(m, off, 64));
    if (lane == 0) red[w] = m;
    __syncthreads();
    m = fmaxf(fmaxf(red[0], red[1]), fmaxf(red[2], red[3]));
    float s = 0.f;
#pragma unroll
    for (int i = 0; i < 4; i++) {
        float e = expf(myv[i] - m);
        sc[tid + i * 256] = e;
        s += e;
    }
#pragma unroll
    for (int off = 32; off >= 1; off >>= 1) s += __shfl_xor(s, off, 64);
    if (lane == 0) red[4 + w] = s;
    __syncthreads();
    float inv = 1.0f / (red[4] + red[5] + red[6] + red[7]);
    const unsigned short* vb = vbuf + (size_t)b * 1024 * 512 + h * DH_;
    int ng = lane >> 3, d8 = (lane & 7) << 3;   // 8 n-groups x 8 dims/lane
    float a[8] = {};
    int n0 = w * 256;
    for (int i = 0; i < 32; i++) {
        int n = n0 + i * 8 + ng;
        uint4 pv = *(const uint4*)(vb + (size_t)n * 512 + d8);
        float sv = sc[n];
        a[0] += sv * bf2f(pv.x);
        a[1] += sv * bf2f(pv.x >> 16);
        a[2] += sv * bf2f(pv.y);
        a[3] += sv * bf2f(pv.y >> 16);
        a[4] += sv * bf2f(pv.z);
        a[5] += sv * bf2f(pv.z >> 16);
        a[6] += sv * bf2f(pv.w);
        a[7] += sv * bf2f(pv.w >> 16);
    }
#pragma unroll
    for (int j = 0; j < 8; j++) {
        a[j] += __shfl_xor(a[j], 8, 64);
        a[j] += __shfl_xor(a[j], 16, 64);
        a[j] += __shfl_xor(a[j], 32, 64);
    }
    if (lane < 8) {
#pragma unroll
        for (int j = 0; j < 8; j++) opart[w][d8 + j] = a[j];
    }
    __syncthreads();
    if (tid < DH_) {
        float r = (opart[0][tid] + opart[1][tid] + opart[2][tid] + opart[3][tid]) * inv;
        o_bf[(size_t)b * E_ + h * DH_ + tid] = f2bf(r);
    }
}

// ---------------- reduce oproj pre (f32) + LN(o) + LN(z) ----------------
__global__ __launch_bounds__(256) void reduce_oln_kernel(const float* __restrict__ opre,
                                                         const float* __restrict__ bout,
                                                         const float* __restrict__ og,
                                                         const float* __restrict__ obv,
                                                         const float* __restrict__ z,
                                                         const float* __restrict__ zg,
                                                         const float* __restrict__ zbv,
                                                         unsigned short* __restrict__ u_bf,
                                                         unsigned short* __restrict__ fused_bf,
                                                         float* __restrict__ zn32) {
    int b = blockIdx.x, tid = threadIdx.x;
    __shared__ float red[16];
    float v[2];
#pragma unroll
    for (int i = 0; i < 2; i++) {
        int e = tid + i * 256;
        v[i] = opre[(size_t)b * E_ + e] + bout[e];
    }
    int w = tid >> 6, lane = tid & 63;
    float s1 = v[0] + v[1];
    float s2 = v[0] * v[0] + v[1] * v[1];
#pragma unroll
    for (int off = 32; off >= 1; off >>= 1) { s1 += __shfl_xor(s1, off, 64); s2 += __shfl_xor(s2, off, 64); }
    if (lane == 0) { red[w] = s1; red[4 + w] = s2; }
    __syncthreads();
    s1 = red[0] + red[1] + red[2] + red[3];
    s2 = red[4] + red[5] + red[6] + red[7];
    float mean = s1 * (1.0f / 512.0f);
    float var = s2 * (1.0f / 512.0f) - mean * mean;
    float rstd = 1.0f / sqrtf(var + 1e-5f);
#pragma unroll
    for (int i = 0; i < 2; i++) {
        int e = tid + i * 256;
        unsigned short val = f2bf((v[i] - mean) * rstd * og[e] + obv[e]);
        u_bf[(size_t)b * 1536 + D_ + e] = val;
        fused_bf[(size_t)b * 1536 + D_ + e] = val;
    }
    float zl[4];
    float t1 = 0.f, t2 = 0.f;
#pragma unroll
    for (int i = 0; i < 4; i++) {
        int d = tid + i * 256;
        zl[i] = z[(size_t)b * D_ + d];
        t1 += zl[i]; t2 += zl[i] * zl[i];
    }
#pragma unroll
    for (int off = 32; off >= 1; off >>= 1) { t1 += __shfl_xor(t1, off, 64); t2 += __shfl_xor(t2, off, 64); }
    __syncthreads();
    if (lane == 0) { red[8 + w] = t1; red[12 + w] = t2; }
    __syncthreads();
    t1 = red[8] + red[9] + red[10] + red[11];
    t2 = red[12] + red[13] + red[14] + red[15];
    float zmean = t1 * (1.0f / 1024.0f);
    float zvar = t2 * (1.0f / 1024.0f) - zmean * zmean;
    float zr = 1.0f / sqrtf(zvar + 1e-5f);
#pragma unroll
    for (int i = 0; i < 4; i++) {
        int d = tid + i * 256;
        float zn = (zl[i] - zmean) * zr * zg[d] + zbv[d];
        u_bf[(size_t)b * 1536 + d] = f2bf(zn);
        zn32[(size_t)b * D_ + d] = zn;
    }
}

// ---------------- NLM over transposed history Abuf_T [t][d][b], bf16 w1 ----------------
template <int NT>
__global__ __launch_bounds__(256) void nlm_kernel(const float* __restrict__ AbufT,
                                                  const unsigned short* __restrict__ w1g_bf,
                                                  const float* __restrict__ b1g,
                                                  const float* __restrict__ w2g,
                                                  const float* __restrict__ b2g,
                                                  float* __restrict__ z,
                                                  float* __restrict__ zt) {
    __shared__ float w1s[4][2048];
    __shared__ float b1s[4][128];
    __shared__ float w2s[4][128];
    __shared__ float b2s[4][2];
    int tid = threadIdx.x;
    int w = tid >> 6, lane = tid & 63;
    int d = blockIdx.x * 4 + w;
    for (int i = lane * 2; i < 2048; i += 128) {
        unsigned int pk = *(const unsigned int*)(w1g_bf + (size_t)d * 2048 + i);
        w1s[w][i] = bf2f(pk);
        w1s[w][i + 1] = bf2f(pk >> 16);
    }
    for (int i = lane; i < 128; i += 64) {
        b1s[w][i] = b1g[(size_t)d * 128 + i];
        w2s[w][i] = w2g[(size_t)d * 128 + i];
    }
    if (lane < 2) b2s[w][lane] = b2g[d * 2 + lane];
    __syncthreads();
    const int b = lane;
    float av[NT];
#pragma unroll
    for (int s = 0; s < NT; s++) av[s] = AbufT[((size_t)s * D_ + d) * 64 + b];
    constexpr int moff = M_ - NT;
    float o0 = b2s[w][0], o1 = b2s[w][1];
    for (int hh = 0; hh < 64; hh++) {
        float a = b1s[w][hh], bb = b1s[w][hh + 64];
#pragma unroll
        for (int s = 0; s < NT; s++) {
            float x = av[s];
            a += x * w1s[w][(s + moff) * 128 + hh];
            bb += x * w1s[w][(s + moff) * 128 + hh + 64];
        }
        float z1 = a / (1.0f + expf(-bb));
        o0 += z1 * w2s[w][hh * 2];
        o1 += z1 * w2s[w][hh * 2 + 1];
    }
    float zv = o0 / (1.0f + expf(-o1));
    z[(size_t)b * D_ + d] = zv;
    zt[((size_t)b * T_ + (NT - 1)) * D_ + d] = zv;
}

// ---------------- pair-sync update + head + certainty (precomputed decay/invs) ----------------
__global__ __launch_bounds__(256) void synchead_kernel(const float* __restrict__ z,
                                                       const int* __restrict__ act_l, const int* __restrict__ act_r,
                                                       const int* __restrict__ out_l, const int* __restrict__ out_r,
                                                       const float* __restrict__ da, const float* __restrict__ dz,
                                                       const float* __restrict__ invsa_t, const float* __restrict__ invso_t,
                                                       const float* __restrict__ head_w, const float* __restrict__ head_b,
                                                       float* __restrict__ a_a,
                                                       unsigned short* __restrict__ s_a_bf,
                                                       float* __restrict__ a_o,
                                                       float* __restrict__ out_logits, float* __restrict__ out_cert, int t) {
    int b = blockIdx.x, tid = threadIdx.x;
    __shared__ float zv[D_];
    __shared__ float red[4][4];
    for (int i = tid; i < D_; i += 256) zv[i] = z[(size_t)b * D_ + i];
    __syncthreads();
    float l0 = 0.f, l1 = 0.f, l2 = 0.f, l3 = 0.f;
    for (int p = tid; p < P_; p += 256) {
        size_t ip = (size_t)b * P_ + p;
        float aa = da[p] * a_a[ip] + zv[act_l[p]] * zv[act_r[p]];
        a_a[ip] = aa;
        s_a_bf[(size_t)b * P_ + p] = f2bf(aa * invsa_t[p]);
        float ao = dz[p] * a_o[ip] + zv[out_l[p]] * zv[out_r[p]];
        a_o[ip] = ao;
        float so = ao * invso_t[p];
        l0 += so * head_w[p];
        l1 += so * head_w[P_ + p];
        l2 += so * head_w[2 * P_ + p];
        l3 += so * head_w[3 * P_ + p];
    }
    int w = tid >> 6, lane = tid & 63;
#pragma unroll
    for (int off = 32; off >= 1; off >>= 1) {
        l0 += __shfl_xor(l0, off, 64);
        l1 += __shfl_xor(l1, off, 64);
        l2 += __shfl_xor(l2, off, 64);
        l3 += __shfl_xor(l3, off, 64);
    }
    if (lane == 0) { red[w][0] = l0; red[w][1] = l1; red[w][2] = l2; red[w][3] = l3; }
    __syncthreads();
    if (tid == 0) {
        float lg[4];
#pragma unroll
        for (int c = 0; c < 4; c++) {
            lg[c] = red[0][c] + red[1][c] + red[2][c] + red[3][c] + head_b[c];
            out_logits[((size_t)b * C_ + c) * T_ + t] = lg[c];
        }
        float m = fmaxf(fmaxf(lg[0], lg[1]), fmaxf(lg[2], lg[3]));
        float e0 = expf(lg[0] - m), e1 = expf(lg[1] - m), e2 = expf(lg[2] - m), e3 = expf(lg[3] - m);
        float inv = 1.0f / (e0 + e1 + e2 + e3);
        float ent = 0.f, pp;
        pp = fmaxf(e0 * inv, 1e-8f); ent -= pp * logf(pp);
        pp = fmaxf(e1 * inv, 1e-8f); ent -= pp * logf(pp);
        pp = fmaxf(e2 * inv, 1e-8f); ent -= pp * logf(pp);
        pp = fmaxf(e3 * inv, 1e-8f); ent -= pp * logf(pp);
        out_cert[(size_t)b * T_ + t] = 1.0f - ent * (1.0f / 1.3862943611198906f);
    }
}

extern "C" void kernel_launch(void* const* d_in, const int* in_sizes, int n_in,
                              void* d_out, int out_size, void* d_ws, size_t ws_size,
                              hipStream_t stream) {
    const float* kv_tokens  = (const float*)d_in[0];
    const float* raw_r_act  = (const float*)d_in[1];
    const float* raw_r_out  = (const float*)d_in[2];
    const float* q_w        = (const float*)d_in[3];
    const float* q_b        = (const float*)d_in[4];
    const float* in_proj_w  = (const float*)d_in[5];
    const float* in_proj_b  = (const float*)d_in[6];
    const float* out_proj_w = (const float*)d_in[7];
    const float* out_proj_b = (const float*)d_in[8];
    const float* z_ln_g     = (const float*)d_in[9];
    const float* z_ln_b     = (const float*)d_in[10];
    const float* o_ln_g     = (const float*)d_in[11];
    const float* o_ln_b     = (const float*)d_in[12];
    const float* gate_w     = (const float*)d_in[13];
    const float* gate_b     = (const float*)d_in[14];
    const float* cand_w     = (const float*)d_in[15];
    const float* cand_b     = (const float*)d_in[16];
    const float* syn1_w     = (const float*)d_in[17];
    const float* syn1_b     = (const float*)d_in[18];
    const float* syn2_w     = (const float*)d_in[19];
    const float* syn2_b     = (const float*)d_in[20];
    const float* nlm1_w     = (const float*)d_in[21];
    const float* nlm1_b     = (const float*)d_in[22];
    const float* nlm2_w     = (const float*)d_in[23];
    const float* nlm2_b     = (const float*)d_in[24];
    const float* head_w     = (const float*)d_in[25];
    const float* head_b     = (const float*)d_in[26];
    const int* act_l        = (const int*)d_in[27];
    const int* act_r        = (const int*)d_in[28];
    const int* out_l        = (const int*)d_in[29];
    const int* out_r        = (const int*)d_in[30];

    float* out = (float*)d_out;
    float* out_logits = out;                       // [B,C,T]
    float* out_cert = out + B_ * C_ * T_;          // [B,T]
    float* out_zt = out_cert + B_ * T_;            // [B,T,D]

    char* ws = (char*)d_ws;
    size_t off = 0;
    auto alloc = [&](size_t bytes) { void* p = ws + off; off += (bytes + 255) & ~(size_t)255; return p; };
    unsigned short* kv_bf   = (unsigned short*)alloc((size_t)B_ * N_ * E_ * 2);     // 64MB (X)
    unsigned short* vbuf    = (unsigned short*)alloc((size_t)B_ * N_ * E_ * 2);     // 64MB
    unsigned short* Wv_bf   = (unsigned short*)alloc((size_t)E_ * E_ * 2);
    unsigned short* Wq_bf   = (unsigned short*)alloc((size_t)E_ * E_ * 2);
    unsigned short* WkT_bf  = (unsigned short*)alloc((size_t)E_ * E_ * 2);
    unsigned short* qwT_bf  = (unsigned short*)alloc((size_t)P_ * E_ * 2);
    unsigned short* WcT_bf  = (unsigned short*)alloc((size_t)P_ * E_ * 2);
    unsigned short* Gmat    = (unsigned short*)alloc((size_t)4096 * P_ * 2);        // 16MB
    unsigned short* Wgc_bf  = (unsigned short*)alloc((size_t)2048 * 1536 * 2);
    unsigned short* Ws1_bf  = (unsigned short*)alloc((size_t)2048 * 1536 * 2);
    unsigned short* Ws2_bf  = (unsigned short*)alloc((size_t)1024 * 2048 * 2);
    unsigned short* Wout_bf = (unsigned short*)alloc((size_t)E_ * E_ * 2);
    unsigned short* nlm1w_bf= (unsigned short*)alloc((size_t)1024 * 2048 * 2);
    float* bc   = (float*)alloc(E_ * 4);
    float* brv  = (float*)alloc(4096 * 4);
    float* da   = (float*)alloc(P_ * 4);
    float* dzv  = (float*)alloc(P_ * 4);
    float* invsa = (float*)alloc((size_t)T_ * P_ * 4);
    float* invso = (float*)alloc((size_t)T_ * P_ * 4);
    unsigned short* s_a_bf  = (unsigned short*)alloc((size_t)B_ * P_ * 2);
    unsigned short* r_bf    = (unsigned short*)alloc((size_t)B_ * 4096 * 2);
    float* Sbuf = (float*)alloc((size_t)B_ * 8 * N_ * 4);                           // 2MB
    unsigned short* o_bf    = (unsigned short*)alloc((size_t)B_ * E_ * 2);
    unsigned short* u_bf    = (unsigned short*)alloc((size_t)B_ * 1536 * 2);
    unsigned short* fused_bf= (unsigned short*)alloc((size_t)B_ * 1536 * 2);
    unsigned short* tbuf_bf = (unsigned short*)alloc((size_t)B_ * HS_ * 2);
    float* opre = (float*)alloc((size_t)B_ * E_ * 4);
    float* zn32 = (float*)alloc((size_t)B_ * D_ * 4);
    float* a_a  = (float*)alloc((size_t)B_ * P_ * 4);
    float* a_o  = (float*)alloc((size_t)B_ * P_ * 4);
    float* zbuf = (float*)alloc((size_t)B_ * D_ * 4);
    float* AbufT = (float*)alloc((size_t)T_ * D_ * B_ * 4);

    init_kernel<<<512, 256, 0, stream>>>(s_a_bf, a_a, a_o, zbuf,
                                         raw_r_act, raw_r_out, da, dzv, invsa, invso);

    // --- one-time weight prep ---
    cvt_bf16_kernel<<<(B_ * N_ * E_ / 4) / 256, 256, 0, stream>>>(kv_tokens, kv_bf, B_ * N_ * E_ / 4);
    cvt_all_kernel<<<2048, 256, 0, stream>>>(
        in_proj_w + (size_t)2 * E_ * E_, Wv_bf, E_ * E_ / 4,
        in_proj_w, Wq_bf, E_ * E_ / 4,
        out_proj_w, Wout_bf, E_ * E_ / 4,
        syn1_w, Ws1_bf, 2048 * 1536 / 4,
        syn2_w, Ws2_bf, 1024 * 2048 / 4,
        nlm1_w, nlm1w_bf, 1024 * 2048 / 4);
    cvt_ilv_kernel<<<2048, 256, 0, stream>>>(gate_w, cand_w, Wgc_bf);
    transpose_cvt_kernel<<<dim3(16, 16), 256, 0, stream>>>(in_proj_w + (size_t)E_ * E_, WkT_bf, E_, E_);
    transpose_cvt_kernel<<<dim3(P_ / 32, E_ / 32), 256, 0, stream>>>(q_w, qwT_bf, E_, P_);
    bcomb_kernel<<<2, 256, 0, stream>>>(in_proj_w, in_proj_b, q_b, bc);
    br_kernel<<<16, 256, 0, stream>>>(in_proj_w, bc, brv);
    r0_kernel<<<(B_ * 4096) / 256, 256, 0, stream>>>(brv, r_bf);   // r for t=0 (s_a == 0)
    gemm_bt_kernel<false><<<dim3(E_ / 128, P_ / 128), 256, 0, stream>>>(qwT_bf, Wq_bf, nullptr, WcT_bf, P_, E_, E_);
    gemm_hb_kernel<<<dim3(P_ / 128, E_ / 128, NH_), 256, 0, stream>>>(WkT_bf, E_, 64,
                                                                      WcT_bf, E_, 64,
                                                                      Gmat, P_, (size_t)512 * P_, 64);
    // V projection (wide tile: halves A re-reads)
    gemm_bt_wide_kernel<<<dim3(E_ / 256, B_ * N_ / 128), 256, 0, stream>>>(kv_bf, Wv_bf, in_proj_b + 2 * E_,
                                                                           vbuf, B_ * N_, E_, E_);

    for (int t = 0; t < T_; t++) {
        if (t > 0) {
            // r = 0.125 * (s_a @ G^T + br)  [64][4096] bf16
            gemmNK_kernel<0><<<256, 256, 0, stream>>>(s_a_bf, Gmat, brv, nullptr, nullptr, r_bf, 4096, P_);
        }
        // S[b][h][n] = X . r
        scoreX_kernel<<<dim3(8, 64), 256, 0, stream>>>(kv_bf, r_bf, Sbuf);
        // softmax + V
        attnV_kernel<<<B_ * NH_, 256, 0, stream>>>(Sbuf, vbuf, o_bf);
        // opre = o @ Wout^T
        gemmNK_kernel<1><<<32, 256, 0, stream>>>(o_bf, Wout_bf, nullptr, nullptr, nullptr, opre, E_, E_);
        reduce_oln_kernel<<<64, 256, 0, stream>>>(opre, out_proj_b, o_ln_g, o_ln_b,
                                                  zbuf, z_ln_g, z_ln_b, u_bf, fused_bf, zn32);
        gemmNK_kernel<2><<<128, 256, 0, stream>>>(u_bf, Wgc_bf, gate_b, cand_b, zn32, fused_bf, 2048, 1536);
        gemmNK_kernel<3><<<128, 256, 0, stream>>>(fused_bf, Ws1_bf, syn1_b, nullptr, nullptr, tbuf_bf, 2048, 1536);
        gemmNK_kernel<4><<<64, 256, 0, stream>>>(tbuf_bf, Ws2_bf, syn2_b, nullptr, nullptr,
                                                 AbufT + (size_t)t * D_ * 64, 1024, 2048);
        switch (t) {
            case 0:  nlm_kernel<1><<<256, 256, 0, stream>>>(AbufT, nlm1w_bf, nlm1_b, nlm2_w, nlm2_b, zbuf, out_zt); break;
            case 1:  nlm_kernel<2><<<256, 256, 0, stream>>>(AbufT, nlm1w_bf, nlm1_b, nlm2_w, nlm2_b, zbuf, out_zt); break;
            case 2:  nlm_kernel<3><<<256, 256, 0, stream>>>(AbufT, nlm1w_bf, nlm1_b, nlm2_w, nlm2_b, zbuf, out_zt); break;
            case 3:  nlm_kernel<4><<<256, 256, 0, stream>>>(AbufT, nlm1w_bf, nlm1_b, nlm2_w, nlm2_b, zbuf, out_zt); break;
            case 4:  nlm_kernel<5><<<256, 256, 0, stream>>>(AbufT, nlm1w_bf, nlm1_b, nlm2_w, nlm2_b, zbuf, out_zt); break;
            case 5:  nlm_kernel<6><<<256, 256, 0, stream>>>(AbufT, nlm1w_bf, nlm1_b, nlm2_w, nlm2_b, zbuf, out_zt); break;
            case 6:  nlm_kernel<7><<<256, 256, 0, stream>>>(AbufT, nlm1w_bf, nlm1_b, nlm2_w, nlm2_b, zbuf, out_zt); break;
            case 7:  nlm_kernel<8><<<256, 256, 0, stream>>>(AbufT, nlm1w_bf, nlm1_b, nlm2_w, nlm2_b, zbuf, out_zt); break;
            case 8:  nlm_kernel<9><<<256, 256, 0, stream>>>(AbufT, nlm1w_bf, nlm1_b, nlm2_w, nlm2_b, zbuf, out_zt); break;
            case 9:  nlm_kernel<10><<<256, 256, 0, stream>>>(AbufT, nlm1w_bf, nlm1_b, nlm2_w, nlm2_b, zbuf, out_zt); break;
            case 10: nlm_kernel<11><<<256, 256, 0, stream>>>(AbufT, nlm1w_bf, nlm1_b, nlm2_w, nlm2_b, zbuf, out_zt); break;
            default: nlm_kernel<12><<<256, 256, 0, stream>>>(AbufT, nlm1w_bf, nlm1_b, nlm2_w, nlm2_b, zbuf, out_zt); break;
        }
        synchead_kernel<<<64, 256, 0, stream>>>(zbuf, act_l, act_r, out_l, out_r, da, dzv,
                                                invsa + t * P_, invso + t * P_,
                                                head_w, head_b, a_a, s_a_bf, a_o,
                                                out_logits, out_cert, t);
    }
}

// Round 11
// 1276.884 us; speedup vs baseline: 1.0419x; 1.0419x over previous
//
#include <hip/hip_runtime.h>
#include <hip/hip_bf16.h>

#define B_ 64
#define N_ 1024
#define E_ 512
#define D_ 1024
#define M_ 16
#define T_ 12
#define P_ 2048
#define HS_ 2048
#define HN_ 64
#define C_ 4
#define NH_ 8
#define DH_ 64

typedef __attribute__((ext_vector_type(8))) short bf16x8;
typedef __attribute__((ext_vector_type(4))) float f32x4;

__device__ __forceinline__ float bf2f(unsigned int u) {
    union { unsigned int i; float f; } c; c.i = (u & 0xffffu) << 16; return c.f;
}
__device__ __forceinline__ unsigned short f2bf(float f) {
    union { float f; unsigned int i; } c; c.f = f;
    unsigned int x = c.i;
    unsigned int r = x + 0x7fffu + ((x >> 16) & 1u);
    return (unsigned short)(r >> 16);
}

// ---------------- init state + decay/invs tables ----------------
__global__ void init_kernel(unsigned short* s_a_bf, float* a_a, float* a_o, float* z,
                            const float* __restrict__ raw_a, const float* __restrict__ raw_o,
                            float* __restrict__ da, float* __restrict__ dz,
                            float* __restrict__ invsa, float* __restrict__ invso) {
    int i = blockIdx.x * 256 + threadIdx.x;
    if (i < B_ * P_) { a_a[i] = 0.f; a_o[i] = 0.f; s_a_bf[i] = 0; }
    if (i < B_ * D_) z[i] = 0.f;
    if (i < P_) {
        float a = 1.f / (1.f + expf(raw_a[i]));
        float o = 1.f / (1.f + expf(raw_o[i]));
        da[i] = a; dz[i] = o;
        float ba = 1.f, bo = 1.f;
        for (int t = 0; t < T_; t++) {
            ba = a * ba + 1.f;
            bo = o * bo + 1.f;
            invsa[t * P_ + i] = 1.0f / sqrtf(ba + 1e-8f);
            invso[t * P_ + i] = 1.0f / sqrtf(bo + 1e-8f);
        }
    }
}

// ---------------- f32 -> bf16 conversion ----------------
__global__ __launch_bounds__(256) void cvt_bf16_kernel(const float* __restrict__ in,
                                                       unsigned short* __restrict__ out, int n4) {
    int i = blockIdx.x * 256 + threadIdx.x;
    if (i < n4) {
        float4 v = ((const float4*)in)[i];
        ushort4 o;
        o.x = f2bf(v.x); o.y = f2bf(v.y); o.z = f2bf(v.z); o.w = f2bf(v.w);
        ((ushort4*)out)[i] = o;
    }
}

// ---------------- consolidated multi-segment cvt ----------------
__global__ __launch_bounds__(256) void cvt_all_kernel(
    const float* s0, unsigned short* d0, int n0,
    const float* s1, unsigned short* d1, int n1,
    const float* s2, unsigned short* d2, int n2,
    const float* s3, unsigned short* d3, int n3,
    const float* s4, unsigned short* d4, int n4,
    const float* s5, unsigned short* d5, int n5) {
    int total = n0 + n1 + n2 + n3 + n4 + n5;
    for (int i = blockIdx.x * 256 + threadIdx.x; i < total; i += gridDim.x * 256) {
        const float* s; unsigned short* d; int j = i;
        if (j < n0) { s = s0; d = d0; }
        else { j -= n0;
        if (j < n1) { s = s1; d = d1; }
        else { j -= n1;
        if (j < n2) { s = s2; d = d2; }
        else { j -= n2;
        if (j < n3) { s = s3; d = d3; }
        else { j -= n3;
        if (j < n4) { s = s4; d = d4; }
        else { j -= n4; s = s5; d = d5; } } } } }
        float4 v = ((const float4*)s)[j];
        ushort4 o;
        o.x = f2bf(v.x); o.y = f2bf(v.y); o.z = f2bf(v.z); o.w = f2bf(v.w);
        ((ushort4*)d)[j] = o;
    }
}

// ---------------- interleave gate/cand rows ----------------
__global__ __launch_bounds__(256) void cvt_ilv_kernel(const float* __restrict__ g,
                                                      const float* __restrict__ c,
                                                      unsigned short* __restrict__ out) {
    int r = blockIdx.x;  // 0..2047
    const float* src = (r & 1) ? (c + (size_t)(r >> 1) * 1536) : (g + (size_t)(r >> 1) * 1536);
    for (int k = threadIdx.x * 4; k < 1536; k += 1024) {
        float4 v = *(const float4*)(src + k);
        ushort4 o;
        o.x = f2bf(v.x); o.y = f2bf(v.y); o.z = f2bf(v.z); o.w = f2bf(v.w);
        *(ushort4*)(out + (size_t)r * 1536 + k) = o;
    }
}

// ---------------- transpose + cvt: out[c][r] = bf16(in[r][c]) ----------------
__global__ __launch_bounds__(256) void transpose_cvt_kernel(const float* __restrict__ in,
                                                            unsigned short* __restrict__ out,
                                                            int R, int Ccols) {
    __shared__ float tb[32][33];
    int c0 = blockIdx.x * 32, r0 = blockIdx.y * 32;
    int tx = threadIdx.x & 31, ty = threadIdx.x >> 5;
#pragma unroll
    for (int i = 0; i < 32; i += 8) tb[ty + i][tx] = in[(size_t)(r0 + ty + i) * Ccols + c0 + tx];
    __syncthreads();
#pragma unroll
    for (int i = 0; i < 32; i += 8) out[(size_t)(c0 + ty + i) * R + r0 + tx] = f2bf(tb[tx][ty + i]);
}

// ---------------- combined query bias: bc = Wq@q_b + bq ----------------
__global__ __launch_bounds__(256) void bcomb_kernel(const float* __restrict__ in_proj_w,
                                                    const float* __restrict__ in_proj_b,
                                                    const float* __restrict__ q_b,
                                                    float* __restrict__ bc) {
    int e = blockIdx.x * 256 + threadIdx.x;
    if (e < E_) {
        const float* wr = in_proj_w + (size_t)e * E_;
        float s = in_proj_b[e];
        for (int k = 0; k < E_; k += 4) {
            float4 w4 = *(const float4*)(wr + k);
            float4 q4 = *(const float4*)(q_b + k);
            s += w4.x * q4.x + w4.y * q4.y + w4.z * q4.z + w4.w * q4.w;
        }
        bc[e] = s;
    }
}

// ---------------- br[h*512+j] = sum_e Wk[h*64+e][j] * bc[h*64+e] ----------------
__global__ __launch_bounds__(256) void br_kernel(const float* __restrict__ in_proj_w,
                                                 const float* __restrict__ bc,
                                                 float* __restrict__ br) {
    int g = blockIdx.x * 256 + threadIdx.x;  // 0..4095
    int h = g >> 9, j = g & 511;
    const float* Wk = in_proj_w + (size_t)E_ * E_;
    float s = 0.f;
    for (int e = 0; e < 64; e++) {
        s += Wk[(size_t)(h * 64 + e) * E_ + j] * bc[h * 64 + e];
    }
    br[g] = s;
}

// ---------------- r for t=0 (s_a == 0): r_bf[b][j] = bf16(0.125 * br[j]) ----------------
__global__ __launch_bounds__(256) void r0_kernel(const float* __restrict__ brv,
                                                 unsigned short* __restrict__ r_bf) {
    int i = blockIdx.x * 256 + threadIdx.x;  // 0 .. 64*4096-1
    if (i < B_ * 4096) {
        r_bf[i] = f2bf(0.125f * brv[i & 4095]);
    }
}

// ---------------- big bf16 MFMA GEMM (128x128 tile) + XCD swizzle ----------------
template <bool HAS_BIAS>
__global__ __launch_bounds__(256) void gemm_bt_kernel(const unsigned short* __restrict__ A,
                                                      const unsigned short* __restrict__ Bt,
                                                      const float* __restrict__ bias,
                                                      unsigned short* __restrict__ C,
                                                      int M, int N, int K) {
    __shared__ __align__(16) unsigned short ldsA[2][4096];
    __shared__ __align__(16) unsigned short ldsB[2][4096];
    int id = blockIdx.y * gridDim.x + blockIdx.x;
    int nwg = gridDim.x * gridDim.y;
    int swz = (id & 7) * (nwg >> 3) + (id >> 3);
    int bx = swz % gridDim.x, by = swz / gridDim.x;
    int m0 = by * 128;
    int n0 = bx * 128;
    int tid = threadIdx.x;
    int wv = tid >> 6, l = tid & 63;
    int wr = wv >> 1, wc = wv & 1;
    int lr = l & 15, lg = l >> 4;
    f32x4 acc[4][4] = {};

    auto stage = [&](int buf, int kt) {
        int k0 = kt * 32;
#pragma unroll
        for (int i = 0; i < 2; i++) {
            int tsk = tid + 256 * i;
            int r = tsk >> 2, g = tsk & 3;
            int gs = (g ^ (r & 3)) * 8;
            __builtin_amdgcn_global_load_lds(
                (const __attribute__((address_space(1))) void*)(A + (size_t)(m0 + r) * K + k0 + gs),
                (__attribute__((address_space(3))) void*)&ldsA[buf][tsk * 8], 16, 0, 0);
        }
#pragma unroll
        for (int i = 0; i < 2; i++) {
            int tsk = tid + 256 * i;
            int r = tsk >> 2, g = tsk & 3;
            int gs = (g ^ (r & 3)) * 8;
            __builtin_amdgcn_global_load_lds(
                (const __attribute__((address_space(1))) void*)(Bt + (size_t)(n0 + r) * K + k0 + gs),
                (__attribute__((address_space(3))) void*)&ldsB[buf][tsk * 8], 16, 0, 0);
        }
    };

    int nt = K >> 5;
    stage(0, 0);
    for (int t = 0; t < nt; t++) {
        int cur = t & 1;
        if (t + 1 < nt) {
            stage(cur ^ 1, t + 1);
            asm volatile("s_waitcnt vmcnt(4)" ::: "memory");
        } else {
            asm volatile("s_waitcnt vmcnt(0)" ::: "memory");
        }
        __builtin_amdgcn_s_barrier();
        bf16x8 af[4], bfr[4];
#pragma unroll
        for (int mi = 0; mi < 4; mi++) {
            int r = wr * 64 + mi * 16 + lr;
            af[mi] = *(const bf16x8*)&ldsA[cur][r * 32 + ((lg ^ (r & 3)) << 3)];
        }
#pragma unroll
        for (int ni = 0; ni < 4; ni++) {
            int c = wc * 64 + ni * 16 + lr;
            bfr[ni] = *(const bf16x8*)&ldsB[cur][c * 32 + ((lg ^ (c & 3)) << 3)];
        }
#pragma unroll
        for (int mi = 0; mi < 4; mi++)
#pragma unroll
            for (int ni = 0; ni < 4; ni++)
                acc[mi][ni] = __builtin_amdgcn_mfma_f32_16x16x32_bf16(af[mi], bfr[ni], acc[mi][ni], 0, 0, 0);
        __builtin_amdgcn_s_barrier();
    }
#pragma unroll
    for (int ni = 0; ni < 4; ni++) {
        int col = n0 + wc * 64 + ni * 16 + lr;
        float bv = HAS_BIAS ? bias[col] : 0.0f;
#pragma unroll
        for (int mi = 0; mi < 4; mi++) {
            int row = m0 + wr * 64 + mi * 16 + lg * 4;
#pragma unroll
            for (int r = 0; r < 4; r++) {
                C[(size_t)(row + r) * N + col] = f2bf(acc[mi][ni][r] + bv);
            }
        }
    }
}

// ---------------- batched (z=head) strided GEMM for G ----------------
__global__ __launch_bounds__(256) void gemm_hb_kernel(const unsigned short* __restrict__ A0, int lda, size_t sAz,
                                                      const unsigned short* __restrict__ B0, int ldb, size_t sBz,
                                                      unsigned short* __restrict__ C0, int ldc, size_t sCz,
                                                      int K) {
    __shared__ __align__(16) unsigned short ldsA[2][4096];
    __shared__ __align__(16) unsigned short ldsB[2][4096];
    const unsigned short* A = A0 + blockIdx.z * sAz;
    const unsigned short* Bt = B0 + blockIdx.z * sBz;
    unsigned short* C = C0 + blockIdx.z * sCz;
    int m0 = blockIdx.y * 128, n0 = blockIdx.x * 128;
    int tid = threadIdx.x;
    int wv = tid >> 6, l = tid & 63;
    int wr = wv >> 1, wc = wv & 1;
    int lr = l & 15, lg = l >> 4;
    f32x4 acc[4][4] = {};

    auto stage = [&](int buf, int kt) {
        int k0 = kt * 32;
#pragma unroll
        for (int i = 0; i < 2; i++) {
            int tsk = tid + 256 * i;
            int r = tsk >> 2, g = tsk & 3;
            int gs = (g ^ (r & 3)) * 8;
            __builtin_amdgcn_global_load_lds(
                (const __attribute__((address_space(1))) void*)(A + (size_t)(m0 + r) * lda + k0 + gs),
                (__attribute__((address_space(3))) void*)&ldsA[buf][tsk * 8], 16, 0, 0);
        }
#pragma unroll
        for (int i = 0; i < 2; i++) {
            int tsk = tid + 256 * i;
            int r = tsk >> 2, g = tsk & 3;
            int gs = (g ^ (r & 3)) * 8;
            __builtin_amdgcn_global_load_lds(
                (const __attribute__((address_space(1))) void*)(Bt + (size_t)(n0 + r) * ldb + k0 + gs),
                (__attribute__((address_space(3))) void*)&ldsB[buf][tsk * 8], 16, 0, 0);
        }
    };

    int nt = K >> 5;
    stage(0, 0);
    for (int t = 0; t < nt; t++) {
        int cur = t & 1;
        if (t + 1 < nt) {
            stage(cur ^ 1, t + 1);
            asm volatile("s_waitcnt vmcnt(4)" ::: "memory");
        } else {
            asm volatile("s_waitcnt vmcnt(0)" ::: "memory");
        }
        __builtin_amdgcn_s_barrier();
        bf16x8 af[4], bfr[4];
#pragma unroll
        for (int mi = 0; mi < 4; mi++) {
            int r = wr * 64 + mi * 16 + lr;
            af[mi] = *(const bf16x8*)&ldsA[cur][r * 32 + ((lg ^ (r & 3)) << 3)];
        }
#pragma unroll
        for (int ni = 0; ni < 4; ni++) {
            int c = wc * 64 + ni * 16 + lr;
            bfr[ni] = *(const bf16x8*)&ldsB[cur][c * 32 + ((lg ^ (c & 3)) << 3)];
        }
#pragma unroll
        for (int mi = 0; mi < 4; mi++)
#pragma unroll
            for (int ni = 0; ni < 4; ni++)
                acc[mi][ni] = __builtin_amdgcn_mfma_f32_16x16x32_bf16(af[mi], bfr[ni], acc[mi][ni], 0, 0, 0);
        __builtin_amdgcn_s_barrier();
    }
#pragma unroll
    for (int ni = 0; ni < 4; ni++) {
        int col = n0 + wc * 64 + ni * 16 + lr;
#pragma unroll
        for (int mi = 0; mi < 4; mi++) {
            int row = m0 + wr * 64 + mi * 16 + lg * 4;
#pragma unroll
            for (int r = 0; r < 4; r++) {
                C[(size_t)(row + r) * ldc + col] = f2bf(acc[mi][ni][r]);
            }
        }
    }
}

// ---------------- fused batch-64 GEMM: 64x16 tile, 4-wave K-split, in-block reduce + epilogue ----------------
template <int EPI>
__global__ __launch_bounds__(256) void gemmNK_kernel(const unsigned short* __restrict__ A,
                                                     const unsigned short* __restrict__ W,
                                                     const float* __restrict__ bias0,
                                                     const float* __restrict__ bias1,
                                                     const float* __restrict__ zn32,
                                                     void* __restrict__ outp,
                                                     int N, int K) {
    __shared__ __align__(16) unsigned short ldsA[4][2][2048];
    __shared__ __align__(16) unsigned short ldsB[4][2][512];
    int n0 = blockIdx.x * 16;
    int tid = threadIdx.x;
    int w = tid >> 6, l = tid & 63;
    int Kw = K >> 2;
    int kb = w * Kw;
    int lr = l & 15, lg = l >> 4;
    int ar = l >> 2, ag = l & 3;
    f32x4 acc[4] = {};

    auto stage = [&](int buf, int kt) {
        int k0 = kb + (kt << 5);
#pragma unroll
        for (int i = 0; i < 4; i++) {
            int row = i * 16 + ar;
            int gs = (ag ^ (row & 3)) << 3;
            __builtin_amdgcn_global_load_lds(
                (const __attribute__((address_space(1))) void*)(A + (size_t)row * K + k0 + gs),
                (__attribute__((address_space(3))) void*)&ldsA[w][buf][i * 512 + l * 8], 16, 0, 0);
        }
        {
            int col = ar;
            int gs = (ag ^ (col & 3)) << 3;
            __builtin_amdgcn_global_load_lds(
                (const __attribute__((address_space(1))) void*)(W + (size_t)(n0 + col) * K + k0 + gs),
                (__attribute__((address_space(3))) void*)&ldsB[w][buf][l * 8], 16, 0, 0);
        }
    };

    int nt = Kw >> 5;
    stage(0, 0);
    for (int t = 0; t < nt; t++) {
        int cur = t & 1;
        if (t + 1 < nt) {
            stage(cur ^ 1, t + 1);
            asm volatile("s_waitcnt vmcnt(5)" ::: "memory");
        } else {
            asm volatile("s_waitcnt vmcnt(0)" ::: "memory");
        }
        bf16x8 bf = *(const bf16x8*)&ldsB[w][cur][lr * 32 + ((lg ^ (lr & 3)) << 3)];
#pragma unroll
        for (int mi = 0; mi < 4; mi++) {
            int rr = mi * 16 + lr;
            bf16x8 af = *(const bf16x8*)&ldsA[w][cur][rr * 32 + ((lg ^ (rr & 3)) << 3)];
            acc[mi] = __builtin_amdgcn_mfma_f32_16x16x32_bf16(af, bf, acc[mi], 0, 0, 0);
        }
    }
    __syncthreads();
    float* red = (float*)&ldsA[0][0][0];  // [4][64][16]
#pragma unroll
    for (int mi = 0; mi < 4; mi++) {
        int row = mi * 16 + lg * 4;
#pragma unroll
        for (int q = 0; q < 4; q++) red[w * 1024 + (row + q) * 16 + lr] = acc[mi][q];
    }
    __syncthreads();
    int b = tid >> 2, c4 = (tid & 3) << 2;
    f32x4 s = *(f32x4*)&red[b * 16 + c4];
#pragma unroll
    for (int ww = 1; ww < 4; ww++) {
        f32x4 v = *(f32x4*)&red[ww * 1024 + b * 16 + c4];
        s[0] += v[0]; s[1] += v[1]; s[2] += v[2]; s[3] += v[3];
    }
    int col = n0 + c4;
    if (EPI == 0) {
        unsigned short* out = (unsigned short*)outp;
        ushort4 o;
        o.x = f2bf(0.125f * (s[0] + bias0[col + 0]));
        o.y = f2bf(0.125f * (s[1] + bias0[col + 1]));
        o.z = f2bf(0.125f * (s[2] + bias0[col + 2]));
        o.w = f2bf(0.125f * (s[3] + bias0[col + 3]));
        *(ushort4*)(out + (size_t)b * N + col) = o;
    } else if (EPI == 1) {
        float* out = (float*)outp;
        *(f32x4*)(out + (size_t)b * N + col) = s;
    } else if (EPI == 2) {
        unsigned short* out = (unsigned short*)outp;
        int j0 = col >> 1;
#pragma unroll
        for (int pp = 0; pp < 2; pp++) {
            int j = j0 + pp;
            float g = 1.0f / (1.0f + expf(-(s[pp * 2] + bias0[j])));
            float h = tanhf(s[pp * 2 + 1] + bias1[j]);
            float zb = (1.0f - g) * zn32[(size_t)b * D_ + j] + g * h;
            out[(size_t)b * 1536 + j] = f2bf(zb);
        }
    } else if (EPI == 3) {
        unsigned short* out = (unsigned short*)outp;
        ushort4 o;
#pragma unroll
        for (int j = 0; j < 4; j++) {
            float pre = s[j] + bias0[col + j];
            float val = 0.5f * pre * (1.0f + erff(pre * 0.70710678118654752f));
            ((unsigned short*)&o)[j] = f2bf(val);
        }
        *(ushort4*)(out + (size_t)b * N + col) = o;
    } else {  // EPI == 4: transposed f32 out[col][b]
        float* out = (float*)outp;
#pragma unroll
        for (int j = 0; j < 4; j++) {
            out[(size_t)(col + j) * 64 + b] = s[j] + bias0[col + j];
        }
    }
}

// ---------------- scores: S[b][h][n] = X[b,n,:] . r[b][h*512+:] (MFMA) ----------------
__global__ __launch_bounds__(256) void scoreX_kernel(const unsigned short* __restrict__ X,
                                                     const unsigned short* __restrict__ r_bf,
                                                     float* __restrict__ S) {
    int b = blockIdx.y;
    int n0 = blockIdx.x * 128;
    int tid = threadIdx.x;
    int wv = tid >> 6, l = tid & 63;
    int lr = l & 15, lg = l >> 4;
    const unsigned short* Xb = X + ((size_t)b * 1024 + n0) * 512;
    const unsigned short* rb = r_bf + (size_t)b * 4096 + (size_t)(lr & 7) * 512 + lg * 8;
    f32x4 acc[2] = {};
#pragma unroll
    for (int kt = 0; kt < 16; kt++) {
        int k0 = kt * 32;
        bf16x8 bfrag = *(const bf16x8*)(rb + k0);
#pragma unroll
        for (int mi = 0; mi < 2; mi++) {
            int row = (wv * 2 + mi) * 16 + lr;
            bf16x8 afrag = *(const bf16x8*)(Xb + (size_t)row * 512 + k0 + lg * 8);
            acc[mi] = __builtin_amdgcn_mfma_f32_16x16x32_bf16(afrag, bfrag, acc[mi], 0, 0, 0);
        }
    }
    if (lr < 8) {
#pragma unroll
        for (int mi = 0; mi < 2; mi++) {
            int rowbase = (wv * 2 + mi) * 16 + lg * 4;
#pragma unroll
            for (int q = 0; q < 4; q++) {
                S[((size_t)b * 8 + lr) * 1024 + n0 + rowbase + q] = acc[mi][q];
            }
        }
    }
}

// ---------------- softmax(S) + V-pass per (b,h) ----------------
__global__ __launch_bounds__(256) void attnV_kernel(const float* __restrict__ S,
                                                    const unsigned short* __restrict__ vbuf,
                                                    unsigned short* __restrict__ o_bf) {
    int bh = blockIdx.x;
    int b = bh >> 3, h = bh & 7;
    __shared__ float sc[N_];
    __shared__ float red[8];
    __shared__ float opart[4][DH_];
    int tid = threadIdx.x;
    int w = tid >> 6, lane = tid & 63;
    const float* Ss = S + ((size_t)b * 8 + h) * 1024;
    float myv[4];
#pragma unroll
    for (int i = 0; i < 4; i++) myv[i] = Ss[tid + i * 256];
    float m = fmaxf(fmaxf(myv[0], myv[1]), fmaxf(myv[2], myv[3]));
#pragma unroll
    for (int off = 32; off >= 1; off >>= 1) m = fmaxf(m, __shfl_xor(m, off, 64));
    if (lane == 0) red[w] = m;
    __syncthreads();
    m = fmaxf(fmaxf(red[0], red[1]), fmaxf(red[2], red[3]));
    float s = 0.f;
#pragma unroll
    for (int i = 0; i < 4; i++) {
        float e = expf(myv[i] - m);
        sc[tid + i * 256] = e;
        s += e;
    }
#pragma unroll
    for (int off = 32; off >= 1; off >>= 1) s += __shfl_xor(s, off, 64);
    if (lane == 0) red[4 + w] = s;
    __syncthreads();
    float inv = 1.0f / (red[4] + red[5] + red[6] + red[7]);
    const unsigned short* vb = vbuf + (size_t)b * 1024 * 512 + h * DH_;
    int ng = lane >> 4, d4 = (lane & 15) << 2;
    float a0 = 0.f, a1 = 0.f, a2 = 0.f, a3 = 0.f;
    int n0 = w * 256;
    for (int i = 0; i < 64; i++) {
        int n = n0 + i * 4 + ng;
        uint2 pv = *(const uint2*)(vb + (size_t)n * 512 + d4);
        float sv = sc[n];
        a0 += sv * bf2f(pv.x);
        a1 += sv * bf2f(pv.x >> 16);
        a2 += sv * bf2f(pv.y);
        a3 += sv * bf2f(pv.y >> 16);
    }
    a0 += __shfl_xor(a0, 16, 64); a0 += __shfl_xor(a0, 32, 64);
    a1 += __shfl_xor(a1, 16, 64); a1 += __shfl_xor(a1, 32, 64);
    a2 += __shfl_xor(a2, 16, 64); a2 += __shfl_xor(a2, 32, 64);
    a3 += __shfl_xor(a3, 16, 64); a3 += __shfl_xor(a3, 32, 64);
    if (lane < 16) {
        opart[w][d4 + 0] = a0;
        opart[w][d4 + 1] = a1;
        opart[w][d4 + 2] = a2;
        opart[w][d4 + 3] = a3;
    }
    __syncthreads();
    if (tid < DH_) {
        float r = (opart[0][tid] + opart[1][tid] + opart[2][tid] + opart[3][tid]) * inv;
        o_bf[(size_t)b * E_ + h * DH_ + tid] = f2bf(r);
    }
}

// ---------------- reduce oproj pre (f32) + LN(o) + LN(z) ----------------
__global__ __launch_bounds__(256) void reduce_oln_kernel(const float* __restrict__ opre,
                                                         const float* __restrict__ bout,
                                                         const float* __restrict__ og,
                                                         const float* __restrict__ obv,
                                                         const float* __restrict__ z,
                                                         const float* __restrict__ zg,
                                                         const float* __restrict__ zbv,
                                                         unsigned short* __restrict__ u_bf,
                                                         unsigned short* __restrict__ fused_bf,
                                                         float* __restrict__ zn32) {
    int b = blockIdx.x, tid = threadIdx.x;
    __shared__ float red[16];
    float v[2];
#pragma unroll
    for (int i = 0; i < 2; i++) {
        int e = tid + i * 256;
        v[i] = opre[(size_t)b * E_ + e] + bout[e];
    }
    int w = tid >> 6, lane = tid & 63;
    float s1 = v[0] + v[1];
    float s2 = v[0] * v[0] + v[1] * v[1];
#pragma unroll
    for (int off = 32; off >= 1; off >>= 1) { s1 += __shfl_xor(s1, off, 64); s2 += __shfl_xor(s2, off, 64); }
    if (lane == 0) { red[w] = s1; red[4 + w] = s2; }
    __syncthreads();
    s1 = red[0] + red[1] + red[2] + red[3];
    s2 = red[4] + red[5] + red[6] + red[7];
    float mean = s1 * (1.0f / 512.0f);
    float var = s2 * (1.0f / 512.0f) - mean * mean;
    float rstd = 1.0f / sqrtf(var + 1e-5f);
#pragma unroll
    for (int i = 0; i < 2; i++) {
        int e = tid + i * 256;
        unsigned short val = f2bf((v[i] - mean) * rstd * og[e] + obv[e]);
        u_bf[(size_t)b * 1536 + D_ + e] = val;
        fused_bf[(size_t)b * 1536 + D_ + e] = val;
    }
    float zl[4];
    float t1 = 0.f, t2 = 0.f;
#pragma unroll
    for (int i = 0; i < 4; i++) {
        int d = tid + i * 256;
        zl[i] = z[(size_t)b * D_ + d];
        t1 += zl[i]; t2 += zl[i] * zl[i];
    }
#pragma unroll
    for (int off = 32; off >= 1; off >>= 1) { t1 += __shfl_xor(t1, off, 64); t2 += __shfl_xor(t2, off, 64); }
    __syncthreads();
    if (lane == 0) { red[8 + w] = t1; red[12 + w] = t2; }
    __syncthreads();
    t1 = red[8] + red[9] + red[10] + red[11];
    t2 = red[12] + red[13] + red[14] + red[15];
    float zmean = t1 * (1.0f / 1024.0f);
    float zvar = t2 * (1.0f / 1024.0f) - zmean * zmean;
    float zr = 1.0f / sqrtf(zvar + 1e-5f);
#pragma unroll
    for (int i = 0; i < 4; i++) {
        int d = tid + i * 256;
        float zn = (zl[i] - zmean) * zr * zg[d] + zbv[d];
        u_bf[(size_t)b * 1536 + d] = f2bf(zn);
        zn32[(size_t)b * D_ + d] = zn;
    }
}

// ---------------- NLM over transposed history Abuf_T [t][d][b], bf16 w1 ----------------
template <int NT>
__global__ __launch_bounds__(256) void nlm_kernel(const float* __restrict__ AbufT,
                                                  const unsigned short* __restrict__ w1g_bf,
                                                  const float* __restrict__ b1g,
                                                  const float* __restrict__ w2g,
                                                  const float* __restrict__ b2g,
                                                  float* __restrict__ z,
                                                  float* __restrict__ zt) {
    __shared__ float w1s[4][2048];
    __shared__ float b1s[4][128];
    __shared__ float w2s[4][128];
    __shared__ float b2s[4][2];
    int tid = threadIdx.x;
    int w = tid >> 6, lane = tid & 63;
    int d = blockIdx.x * 4 + w;
    for (int i = lane * 2; i < 2048; i += 128) {
        unsigned int pk = *(const unsigned int*)(w1g_bf + (size_t)d * 2048 + i);
        w1s[w][i] = bf2f(pk);
        w1s[w][i + 1] = bf2f(pk >> 16);
    }
    for (int i = lane; i < 128; i += 64) {
        b1s[w][i] = b1g[(size_t)d * 128 + i];
        w2s[w][i] = w2g[(size_t)d * 128 + i];
    }
    if (lane < 2) b2s[w][lane] = b2g[d * 2 + lane];
    __syncthreads();
    const int b = lane;
    float av[NT];
#pragma unroll
    for (int s = 0; s < NT; s++) av[s] = AbufT[((size_t)s * D_ + d) * 64 + b];
    constexpr int moff = M_ - NT;
    float o0 = b2s[w][0], o1 = b2s[w][1];
    for (int hh = 0; hh < 64; hh++) {
        float a = b1s[w][hh], bb = b1s[w][hh + 64];
#pragma unroll
        for (int s = 0; s < NT; s++) {
            float x = av[s];
            a += x * w1s[w][(s + moff) * 128 + hh];
            bb += x * w1s[w][(s + moff) * 128 + hh + 64];
        }
        float z1 = a / (1.0f + expf(-bb));
        o0 += z1 * w2s[w][hh * 2];
        o1 += z1 * w2s[w][hh * 2 + 1];
    }
    float zv = o0 / (1.0f + expf(-o1));
    z[(size_t)b * D_ + d] = zv;
    zt[((size_t)b * T_ + (NT - 1)) * D_ + d] = zv;
}

// ---------------- pair-sync update + head + certainty (precomputed decay/invs) ----------------
__global__ __launch_bounds__(256) void synchead_kernel(const float* __restrict__ z,
                                                       const int* __restrict__ act_l, const int* __restrict__ act_r,
                                                       const int* __restrict__ out_l, const int* __restrict__ out_r,
                                                       const float* __restrict__ da, const float* __restrict__ dz,
                                                       const float* __restrict__ invsa_t, const float* __restrict__ invso_t,
                                                       const float* __restrict__ head_w, const float* __restrict__ head_b,
                                                       float* __restrict__ a_a,
                                                       unsigned short* __restrict__ s_a_bf,
                                                       float* __restrict__ a_o,
                                                       float* __restrict__ out_logits, float* __restrict__ out_cert, int t) {
    int b = blockIdx.x, tid = threadIdx.x;
    __shared__ float zv[D_];
    __shared__ float red[4][4];
    for (int i = tid; i < D_; i += 256) zv[i] = z[(size_t)b * D_ + i];
    __syncthreads();
    float l0 = 0.f, l1 = 0.f, l2 = 0.f, l3 = 0.f;
    for (int p = tid; p < P_; p += 256) {
        size_t ip = (size_t)b * P_ + p;
        float aa = da[p] * a_a[ip] + zv[act_l[p]] * zv[act_r[p]];
        a_a[ip] = aa;
        s_a_bf[(size_t)b * P_ + p] = f2bf(aa * invsa_t[p]);
        float ao = dz[p] * a_o[ip] + zv[out_l[p]] * zv[out_r[p]];
        a_o[ip] = ao;
        float so = ao * invso_t[p];
        l0 += so * head_w[p];
        l1 += so * head_w[P_ + p];
        l2 += so * head_w[2 * P_ + p];
        l3 += so * head_w[3 * P_ + p];
    }
    int w = tid >> 6, lane = tid & 63;
#pragma unroll
    for (int off = 32; off >= 1; off >>= 1) {
        l0 += __shfl_xor(l0, off, 64);
        l1 += __shfl_xor(l1, off, 64);
        l2 += __shfl_xor(l2, off, 64);
        l3 += __shfl_xor(l3, off, 64);
    }
    if (lane == 0) { red[w][0] = l0; red[w][1] = l1; red[w][2] = l2; red[w][3] = l3; }
    __syncthreads();
    if (tid == 0) {
        float lg[4];
#pragma unroll
        for (int c = 0; c < 4; c++) {
            lg[c] = red[0][c] + red[1][c] + red[2][c] + red[3][c] + head_b[c];
            out_logits[((size_t)b * C_ + c) * T_ + t] = lg[c];
        }
        float m = fmaxf(fmaxf(lg[0], lg[1]), fmaxf(lg[2], lg[3]));
        float e0 = expf(lg[0] - m), e1 = expf(lg[1] - m), e2 = expf(lg[2] - m), e3 = expf(lg[3] - m);
        float inv = 1.0f / (e0 + e1 + e2 + e3);
        float ent = 0.f, pp;
        pp = fmaxf(e0 * inv, 1e-8f); ent -= pp * logf(pp);
        pp = fmaxf(e1 * inv, 1e-8f); ent -= pp * logf(pp);
        pp = fmaxf(e2 * inv, 1e-8f); ent -= pp * logf(pp);
        pp = fmaxf(e3 * inv, 1e-8f); ent -= pp * logf(pp);
        out_cert[(size_t)b * T_ + t] = 1.0f - ent * (1.0f / 1.3862943611198906f);
    }
}

extern "C" void kernel_launch(void* const* d_in, const int* in_sizes, int n_in,
                              void* d_out, int out_size, void* d_ws, size_t ws_size,
                              hipStream_t stream) {
    const float* kv_tokens  = (const float*)d_in[0];
    const float* raw_r_act  = (const float*)d_in[1];
    const float* raw_r_out  = (const float*)d_in[2];
    const float* q_w        = (const float*)d_in[3];
    const float* q_b        = (const float*)d_in[4];
    const float* in_proj_w  = (const float*)d_in[5];
    const float* in_proj_b  = (const float*)d_in[6];
    const float* out_proj_w = (const float*)d_in[7];
    const float* out_proj_b = (const float*)d_in[8];
    const float* z_ln_g     = (const float*)d_in[9];
    const float* z_ln_b     = (const float*)d_in[10];
    const float* o_ln_g     = (const float*)d_in[11];
    const float* o_ln_b     = (const float*)d_in[12];
    const float* gate_w     = (const float*)d_in[13];
    const float* gate_b     = (const float*)d_in[14];
    const float* cand_w     = (const float*)d_in[15];
    const float* cand_b     = (const float*)d_in[16];
    const float* syn1_w     = (const float*)d_in[17];
    const float* syn1_b     = (const float*)d_in[18];
    const float* syn2_w     = (const float*)d_in[19];
    const float* syn2_b     = (const float*)d_in[20];
    const float* nlm1_w     = (const float*)d_in[21];
    const float* nlm1_b     = (const float*)d_in[22];
    const float* nlm2_w     = (const float*)d_in[23];
    const float* nlm2_b     = (const float*)d_in[24];
    const float* head_w     = (const float*)d_in[25];
    const float* head_b     = (const float*)d_in[26];
    const int* act_l        = (const int*)d_in[27];
    const int* act_r        = (const int*)d_in[28];
    const int* out_l        = (const int*)d_in[29];
    const int* out_r        = (const int*)d_in[30];

    float* out = (float*)d_out;
    float* out_logits = out;                       // [B,C,T]
    float* out_cert = out + B_ * C_ * T_;          // [B,T]
    float* out_zt = out_cert + B_ * T_;            // [B,T,D]

    char* ws = (char*)d_ws;
    size_t off = 0;
    auto alloc = [&](size_t bytes) { void* p = ws + off; off += (bytes + 255) & ~(size_t)255; return p; };
    unsigned short* kv_bf   = (unsigned short*)alloc((size_t)B_ * N_ * E_ * 2);     // 64MB (X)
    unsigned short* vbuf    = (unsigned short*)alloc((size_t)B_ * N_ * E_ * 2);     // 64MB
    unsigned short* Wv_bf   = (unsigned short*)alloc((size_t)E_ * E_ * 2);
    unsigned short* Wq_bf   = (unsigned short*)alloc((size_t)E_ * E_ * 2);
    unsigned short* WkT_bf  = (unsigned short*)alloc((size_t)E_ * E_ * 2);
    unsigned short* qwT_bf  = (unsigned short*)alloc((size_t)P_ * E_ * 2);
    unsigned short* WcT_bf  = (unsigned short*)alloc((size_t)P_ * E_ * 2);
    unsigned short* Gmat    = (unsigned short*)alloc((size_t)4096 * P_ * 2);        // 16MB
    unsigned short* Wgc_bf  = (unsigned short*)alloc((size_t)2048 * 1536 * 2);
    unsigned short* Ws1_bf  = (unsigned short*)alloc((size_t)2048 * 1536 * 2);
    unsigned short* Ws2_bf  = (unsigned short*)alloc((size_t)1024 * 2048 * 2);
    unsigned short* Wout_bf = (unsigned short*)alloc((size_t)E_ * E_ * 2);
    unsigned short* nlm1w_bf= (unsigned short*)alloc((size_t)1024 * 2048 * 2);
    float* bc   = (float*)alloc(E_ * 4);
    float* brv  = (float*)alloc(4096 * 4);
    float* da   = (float*)alloc(P_ * 4);
    float* dzv  = (float*)alloc(P_ * 4);
    float* invsa = (float*)alloc((size_t)T_ * P_ * 4);
    float* invso = (float*)alloc((size_t)T_ * P_ * 4);
    unsigned short* s_a_bf  = (unsigned short*)alloc((size_t)B_ * P_ * 2);
    unsigned short* r_bf    = (unsigned short*)alloc((size_t)B_ * 4096 * 2);
    float* Sbuf = (float*)alloc((size_t)B_ * 8 * N_ * 4);                           // 2MB
    unsigned short* o_bf    = (unsigned short*)alloc((size_t)B_ * E_ * 2);
    unsigned short* u_bf    = (unsigned short*)alloc((size_t)B_ * 1536 * 2);
    unsigned short* fused_bf= (unsigned short*)alloc((size_t)B_ * 1536 * 2);
    unsigned short* tbuf_bf = (unsigned short*)alloc((size_t)B_ * HS_ * 2);
    float* opre = (float*)alloc((size_t)B_ * E_ * 4);
    float* zn32 = (float*)alloc((size_t)B_ * D_ * 4);
    float* a_a  = (float*)alloc((size_t)B_ * P_ * 4);
    float* a_o  = (float*)alloc((size_t)B_ * P_ * 4);
    float* zbuf = (float*)alloc((size_t)B_ * D_ * 4);
    float* AbufT = (float*)alloc((size_t)T_ * D_ * B_ * 4);

    init_kernel<<<512, 256, 0, stream>>>(s_a_bf, a_a, a_o, zbuf,
                                         raw_r_act, raw_r_out, da, dzv, invsa, invso);

    // --- one-time weight prep ---
    cvt_bf16_kernel<<<(B_ * N_ * E_ / 4) / 256, 256, 0, stream>>>(kv_tokens, kv_bf, B_ * N_ * E_ / 4);
    cvt_all_kernel<<<2048, 256, 0, stream>>>(
        in_proj_w + (size_t)2 * E_ * E_, Wv_bf, E_ * E_ / 4,
        in_proj_w, Wq_bf, E_ * E_ / 4,
        out_proj_w, Wout_bf, E_ * E_ / 4,
        syn1_w, Ws1_bf, 2048 * 1536 / 4,
        syn2_w, Ws2_bf, 1024 * 2048 / 4,
        nlm1_w, nlm1w_bf, 1024 * 2048 / 4);
    cvt_ilv_kernel<<<2048, 256, 0, stream>>>(gate_w, cand_w, Wgc_bf);
    transpose_cvt_kernel<<<dim3(16, 16), 256, 0, stream>>>(in_proj_w + (size_t)E_ * E_, WkT_bf, E_, E_);
    transpose_cvt_kernel<<<dim3(P_ / 32, E_ / 32), 256, 0, stream>>>(q_w, qwT_bf, E_, P_);
    bcomb_kernel<<<2, 256, 0, stream>>>(in_proj_w, in_proj_b, q_b, bc);
    br_kernel<<<16, 256, 0, stream>>>(in_proj_w, bc, brv);
    r0_kernel<<<(B_ * 4096) / 256, 256, 0, stream>>>(brv, r_bf);   // r for t=0 (s_a == 0)
    gemm_bt_kernel<false><<<dim3(E_ / 128, P_ / 128), 256, 0, stream>>>(qwT_bf, Wq_bf, nullptr, WcT_bf, P_, E_, E_);
    gemm_hb_kernel<<<dim3(P_ / 128, E_ / 128, NH_), 256, 0, stream>>>(WkT_bf, E_, 64,
                                                                      WcT_bf, E_, 64,
                                                                      Gmat, P_, (size_t)512 * P_, 64);
    // V projection only (K never materialized)
    gemm_bt_kernel<true><<<dim3(E_ / 128, B_ * N_ / 128), 256, 0, stream>>>(kv_bf, Wv_bf, in_proj_b + 2 * E_,
                                                                            vbuf, B_ * N_, E_, E_);

    for (int t = 0; t < T_; t++) {
        if (t > 0) {
            // r = 0.125 * (s_a @ G^T + br)  [64][4096] bf16
            gemmNK_kernel<0><<<256, 256, 0, stream>>>(s_a_bf, Gmat, brv, nullptr, nullptr, r_bf, 4096, P_);
        }
        // S[b][h][n] = X . r
        scoreX_kernel<<<dim3(8, 64), 256, 0, stream>>>(kv_bf, r_bf, Sbuf);
        // softmax + V
        attnV_kernel<<<B_ * NH_, 256, 0, stream>>>(Sbuf, vbuf, o_bf);
        // opre = o @ Wout^T
        gemmNK_kernel<1><<<32, 256, 0, stream>>>(o_bf, Wout_bf, nullptr, nullptr, nullptr, opre, E_, E_);
        reduce_oln_kernel<<<64, 256, 0, stream>>>(opre, out_proj_b, o_ln_g, o_ln_b,
                                                  zbuf, z_ln_g, z_ln_b, u_bf, fused_bf, zn32);
        gemmNK_kernel<2><<<128, 256, 0, stream>>>(u_bf, Wgc_bf, gate_b, cand_b, zn32, fused_bf, 2048, 1536);
        gemmNK_kernel<3><<<128, 256, 0, stream>>>(fused_bf, Ws1_bf, syn1_b, nullptr, nullptr, tbuf_bf, 2048, 1536);
        gemmNK_kernel<4><<<64, 256, 0, stream>>>(tbuf_bf, Ws2_bf, syn2_b, nullptr, nullptr,
                                                 AbufT + (size_t)t * D_ * 64, 1024, 2048);
        switch (t) {
            case 0:  nlm_kernel<1><<<256, 256, 0, stream>>>(AbufT, nlm1w_bf, nlm1_b, nlm2_w, nlm2_b, zbuf, out_zt); break;
            case 1:  nlm_kernel<2><<<256, 256, 0, stream>>>(AbufT, nlm1w_bf, nlm1_b, nlm2_w, nlm2_b, zbuf, out_zt); break;
            case 2:  nlm_kernel<3><<<256, 256, 0, stream>>>(AbufT, nlm1w_bf, nlm1_b, nlm2_w, nlm2_b, zbuf, out_zt); break;
            case 3:  nlm_kernel<4><<<256, 256, 0, stream>>>(AbufT, nlm1w_bf, nlm1_b, nlm2_w, nlm2_b, zbuf, out_zt); break;
            case 4:  nlm_kernel<5><<<256, 256, 0, stream>>>(AbufT, nlm1w_bf, nlm1_b, nlm2_w, nlm2_b, zbuf, out_zt); break;
            case 5:  nlm_kernel<6><<<256, 256, 0, stream>>>(AbufT, nlm1w_bf, nlm1_b, nlm2_w, nlm2_b, zbuf, out_zt); break;
            case 6:  nlm_kernel<7><<<256, 256, 0, stream>>>(AbufT, nlm1w_bf, nlm1_b, nlm2_w, nlm2_b, zbuf, out_zt); break;
            case 7:  nlm_kernel<8><<<256, 256, 0, stream>>>(AbufT, nlm1w_bf, nlm1_b, nlm2_w, nlm2_b, zbuf, out_zt); break;
            case 8:  nlm_kernel<9><<<256, 256, 0, stream>>>(AbufT, nlm1w_bf, nlm1_b, nlm2_w, nlm2_b, zbuf, out_zt); break;
            case 9:  nlm_kernel<10><<<256, 256, 0, stream>>>(AbufT, nlm1w_bf, nlm1_b, nlm2_w, nlm2_b, zbuf, out_zt); break;
            case 10: nlm_kernel<11><<<256, 256, 0, stream>>>(AbufT, nlm1w_bf, nlm1_b, nlm2_w, nlm2_b, zbuf, out_zt); break;
            default: nlm_kernel<12><<<256, 256, 0, stream>>>(AbufT, nlm1w_bf, nlm1_b, nlm2_w, nlm2_b, zbuf, out_zt); break;
        }
        synchead_kernel<<<64, 256, 0, stream>>>(zbuf, act_l, act_r, out_l, out_r, da, dzv,
                                                invsa + t * P_, invso + t * P_,
                                                head_w, head_b, a_a, s_a_bf, a_o,
                                                out_logits, out_cert, t);
    }
}